// Round 4
// baseline (40.959 us; speedup 1.0000x reference)
//
#include <hip/hip_runtime.h>
#include <hip/hip_bf16.h>

#define C_ 10
#define B_ 8192
#define F_ 256
#define O_ 64
#define DK_ 5
#define NBLK1 256   // k1 blocks -> partial count

typedef __attribute__((ext_vector_type(8))) short short8;
typedef __attribute__((ext_vector_type(4))) float floatx4;

static __device__ __forceinline__ unsigned short f2bf(float f) {
    union { float f; unsigned u; } v; v.f = f;
    unsigned r = v.u + 0x7fffu + ((v.u >> 16) & 1u);  // round-nearest-even
    return (unsigned short)(r >> 16);
}

// ---------------- K1: per-block partial G + emit x as bf16 ------------------
// G_part[blk][c][f] = sum_{b in block} x[b,f]*y[b,c]   (no atomics, no memset)
__global__ __launch_bounds__(256) void k1_reduce(const float* __restrict__ x,
                                                 const float* __restrict__ y,
                                                 float* __restrict__ G_part,
                                                 unsigned short* __restrict__ xb) {
    __shared__ float xl[32 * F_];      // 32 KiB
    __shared__ float yl[32 * C_];
    const int b0 = blockIdx.x * 32;
    const int t  = threadIdx.x;

    for (int i = t; i < 32 * C_; i += 256) yl[i] = y[b0 * C_ + i];

    const int r  = t >> 6;             // row sub-slot 0..3
    const int f4 = (t & 63) * 4;       // 4 features per thread
#pragma unroll
    for (int j = 0; j < 8; ++j) {
        int row = r + 4 * j;           // 0..31
        float4 v = *(const float4*)(x + (size_t)(b0 + row) * F_ + f4);
        *(float4*)(xl + row * F_ + f4) = v;
        ushort4 s;
        s.x = f2bf(v.x); s.y = f2bf(v.y); s.z = f2bf(v.z); s.w = f2bf(v.w);
        *(ushort4*)(xb + (size_t)(b0 + row) * F_ + f4) = s;
    }
    __syncthreads();

    float acc[C_];
#pragma unroll
    for (int c = 0; c < C_; ++c) acc[c] = 0.f;

#pragma unroll 8
    for (int b = 0; b < 32; ++b) {
        float xv = xl[b * F_ + t];     // 2-way bank alias (free)
#pragma unroll
        for (int c = 0; c < C_; ++c) acc[c] = fmaf(yl[b * C_ + c], xv, acc[c]);
    }

    float* gp = G_part + (size_t)blockIdx.x * C_ * F_ + t;
#pragma unroll
    for (int c = 0; c < C_; ++c) gp[c * F_] = acc[c];   // coalesced, non-atomic
}

// ---------------- K2: partial-sum + softmax + weight prep. 4 blocks per c ---
// attn2[f] = exp(z-zmax)*w_value[c] (redundant per block);
// WT[c] swizzle-baked bf16 [o][k=f]: byte(o,f) = o*512 + ((2f) ^ ((o&7)<<4))
__global__ __launch_bounds__(256) void k2_wprep(const float* __restrict__ G_part,
                                                const float* __restrict__ w_key,
                                                const float* __restrict__ w_query,
                                                const float* __restrict__ w_value,
                                                const float* __restrict__ weight,
                                                unsigned short* __restrict__ WT) {
    __shared__ float a2[F_];
    __shared__ float wred[4];
    const int c    = blockIdx.x >> 2;
    const int part = blockIdx.x & 3;   // 64 features each for the prep phase
    const int t    = threadIdx.x;

    // sum the 256 per-block partials for (c, f=t): 4-way ILP
    const float* gp = G_part + c * F_ + t;
    float g0 = 0.f, g1 = 0.f, g2 = 0.f, g3 = 0.f;
#pragma unroll 4
    for (int blk = 0; blk < NBLK1; blk += 4) {
        g0 += gp[(size_t)(blk + 0) * C_ * F_];
        g1 += gp[(size_t)(blk + 1) * C_ * F_];
        g2 += gp[(size_t)(blk + 2) * C_ * F_];
        g3 += gp[(size_t)(blk + 3) * C_ * F_];
    }
    float g = (g0 + g1) + (g2 + g3);

    float s = 0.f;
#pragma unroll
    for (int k = 0; k < DK_; ++k) s += w_key[c * DK_ + k] * w_query[c * DK_ + k];

    float z = s * g * (1.0f / (float)B_);
    float m = z;
#pragma unroll
    for (int off = 32; off >= 1; off >>= 1) m = fmaxf(m, __shfl_xor(m, off));
    if ((t & 63) == 0) wred[t >> 6] = m;
    __syncthreads();
    float mm = fmaxf(fmaxf(wred[0], wred[1]), fmaxf(wred[2], wred[3]));
    a2[t] = expf(z - mm) * w_value[c];
    __syncthreads();

    const int o  = t & 63;
    const int fg = t >> 6;
    const float* wsrc = weight + (size_t)c * F_ * O_;
    char* wdst = (char*)(WT + (size_t)c * O_ * F_);
#pragma unroll
    for (int gi = 0; gi < 2; ++gi) {
        int f0 = part * 64 + fg * 16 + gi * 8;
        short8 v8;
#pragma unroll
        for (int e = 0; e < 8; ++e) {
            int f = f0 + e;
            v8[e] = (short)f2bf(wsrc[f * O_ + o] * a2[f]);  // coalesced along o
        }
        int byte = o * 512 + ((2 * f0) ^ ((o & 7) << 4));   // 16B-aligned
        *(short8*)(wdst + byte) = v8;
    }
}

// ---------------- K3: out[c][b][o] = Xbf16 @ WT[c]^T + bias, MFMA 16x16x32 ---
// 64-row tiles, 4 waves x 16 rows, A prefetched to regs before staging barrier
__global__ __launch_bounds__(256) void k3_mfma(const unsigned short* __restrict__ xb,
                                               const unsigned short* __restrict__ WT,
                                               const float* __restrict__ bias,
                                               float* __restrict__ out) {
    __shared__ unsigned short wt[O_ * F_];  // 32 KiB swizzled [o][k]
    const int c  = blockIdx.y;
    const int b0 = blockIdx.x * 64;
    const int t  = threadIdx.x;
    const int w  = t >> 6;
    const int l  = t & 63;
    const int lr = l & 15;
    const int lg = l >> 4;

    // A prefetch: 8 x short8 (row b0+w*16+lr, k = k0*32 + lg*8), issues early
    const unsigned short* xrow = xb + (size_t)(b0 + w * 16 + lr) * F_;
    short8 a[8];
#pragma unroll
    for (int k0 = 0; k0 < 8; ++k0) a[k0] = *(const short8*)(xrow + k0 * 32 + lg * 8);

    // stage WT[c] linearly (swizzle pre-baked)
    {
        const short8* src = (const short8*)(WT + (size_t)c * O_ * F_);
        short8* dst = (short8*)wt;
#pragma unroll
        for (int j = 0; j < 8; ++j) dst[t + 256 * j] = src[t + 256 * j];
    }
    __syncthreads();

    floatx4 acc[4];
#pragma unroll
    for (int n = 0; n < 4; ++n) {
        float bo = bias[c * O_ + n * 16 + lr];
        acc[n] = (floatx4){bo, bo, bo, bo};   // bias folded into C-init
    }

#pragma unroll
    for (int k0 = 0; k0 < 8; ++k0) {
#pragma unroll
        for (int n = 0; n < 4; ++n) {
            int o = n * 16 + lr;
            int byte = o * 512 + ((k0 * 64 + lg * 16) ^ ((o & 7) << 4));
            short8 bf = *(const short8*)((const char*)wt + byte);  // conflict-free
            acc[n] = __builtin_amdgcn_mfma_f32_16x16x32_bf16(a[k0], bf, acc[n], 0, 0, 0);
        }
    }

    // D layout: col = lane&15, row = (lane>>4)*4 + reg
#pragma unroll
    for (int n = 0; n < 4; ++n) {
        int col = n * 16 + lr;
#pragma unroll
        for (int r = 0; r < 4; ++r) {
            int row = b0 + w * 16 + lg * 4 + r;
            out[((size_t)c * B_ + row) * O_ + col] = acc[n][r];
        }
    }
}

extern "C" void kernel_launch(void* const* d_in, const int* in_sizes, int n_in,
                              void* d_out, int out_size, void* d_ws, size_t ws_size,
                              hipStream_t stream) {
    const float* x       = (const float*)d_in[0];
    const float* y       = (const float*)d_in[1];
    const float* w_key   = (const float*)d_in[2];
    const float* w_query = (const float*)d_in[3];
    const float* w_value = (const float*)d_in[4];
    const float* weight  = (const float*)d_in[5];
    const float* bias    = (const float*)d_in[6];
    float* out = (float*)d_out;

    char* ws = (char*)d_ws;
    unsigned short* xb     = (unsigned short*)ws;                      // 4 MiB
    unsigned short* WT     = (unsigned short*)(ws + (size_t)B_ * F_ * 2);        // 320 KiB
    float*          G_part = (float*)(ws + (size_t)B_ * F_ * 2 + C_ * O_ * F_ * 2);  // 2.62 MiB

    k1_reduce<<<NBLK1, 256, 0, stream>>>(x, y, G_part, xb);
    k2_wprep<<<C_ * 4, 256, 0, stream>>>(G_part, w_key, w_query, w_value, weight, WT);
    dim3 g3(B_ / 64, C_);
    k3_mfma<<<g3, 256, 0, stream>>>(xb, WT, bias, out);
}

// Round 5
// 27.723 us; speedup vs baseline: 1.4774x; 1.4774x over previous
//
#include <hip/hip_runtime.h>
#include <hip/hip_bf16.h>

#define C_ 10
#define B_ 8192
#define F_ 256
#define O_ 64
#define DK_ 5
#define NBLK1 256   // k1 blocks -> partial count
#define NG2   16    // second-level partial count

typedef __attribute__((ext_vector_type(8))) short short8;
typedef __attribute__((ext_vector_type(4))) float floatx4;

static __device__ __forceinline__ unsigned short f2bf(float f) {
    union { float f; unsigned u; } v; v.f = f;
    unsigned r = v.u + 0x7fffu + ((v.u >> 16) & 1u);  // round-nearest-even
    return (unsigned short)(r >> 16);
}

// ---------------- K1: per-block partial G + emit x as bf16 ------------------
// G_part[blk][c][f] = sum_{b in block} x[b,f]*y[b,c]   (no atomics, no memset)
__global__ __launch_bounds__(256) void k1_reduce(const float* __restrict__ x,
                                                 const float* __restrict__ y,
                                                 float* __restrict__ G_part,
                                                 unsigned short* __restrict__ xb) {
    __shared__ float xl[32 * F_];      // 32 KiB
    __shared__ float yl[32 * C_];
    const int b0 = blockIdx.x * 32;
    const int t  = threadIdx.x;

    for (int i = t; i < 32 * C_; i += 256) yl[i] = y[b0 * C_ + i];

    const int r  = t >> 6;             // row sub-slot 0..3
    const int f4 = (t & 63) * 4;       // 4 features per thread
#pragma unroll
    for (int j = 0; j < 8; ++j) {
        int row = r + 4 * j;           // 0..31
        float4 v = *(const float4*)(x + (size_t)(b0 + row) * F_ + f4);
        *(float4*)(xl + row * F_ + f4) = v;
        ushort4 s;
        s.x = f2bf(v.x); s.y = f2bf(v.y); s.z = f2bf(v.z); s.w = f2bf(v.w);
        *(ushort4*)(xb + (size_t)(b0 + row) * F_ + f4) = s;
    }
    __syncthreads();

    float acc[C_];
#pragma unroll
    for (int c = 0; c < C_; ++c) acc[c] = 0.f;

#pragma unroll 8
    for (int b = 0; b < 32; ++b) {
        float xv = xl[b * F_ + t];     // 2-way bank alias (free)
#pragma unroll
        for (int c = 0; c < C_; ++c) acc[c] = fmaf(yl[b * C_ + c], xv, acc[c]);
    }

    float* gp = G_part + (size_t)blockIdx.x * C_ * F_ + t;
#pragma unroll
    for (int c = 0; c < C_; ++c) gp[c * F_] = acc[c];   // coalesced, non-atomic
}

// ---------------- K1b: tree fan-in, 16 partials per block, coalesced --------
// G2[g][c][f] = sum_{i<16} G_part[g*16+i][c][f];  grid = C_*NG2 = 160 blocks
__global__ __launch_bounds__(256) void k1b_reduce(const float* __restrict__ G_part,
                                                  float* __restrict__ G2) {
    const int c = (int)blockIdx.x >> 4;
    const int g = (int)blockIdx.x & 15;
    const int t = threadIdx.x;
    const float* gp = G_part + (size_t)(g * 16) * C_ * F_ + c * F_ + t;
    float a0 = 0.f, a1 = 0.f, a2 = 0.f, a3 = 0.f;
#pragma unroll
    for (int i = 0; i < 16; i += 4) {   // 16 independent coalesced 1KB-row loads
        a0 += gp[(size_t)(i + 0) * C_ * F_];
        a1 += gp[(size_t)(i + 1) * C_ * F_];
        a2 += gp[(size_t)(i + 2) * C_ * F_];
        a3 += gp[(size_t)(i + 3) * C_ * F_];
    }
    G2[(size_t)g * C_ * F_ + c * F_ + t] = (a0 + a1) + (a2 + a3);
}

// ---------------- K2: final reduce + softmax + weight prep. 4 blocks per c --
// attn2[f] = exp(z-zmax)*w_value[c] (redundant per block);
// WT[c] swizzle-baked bf16 [o][k=f]: byte(o,f) = o*512 + ((2f) ^ ((o&7)<<4))
__global__ __launch_bounds__(256) void k2_wprep(const float* __restrict__ G2,
                                                const float* __restrict__ w_key,
                                                const float* __restrict__ w_query,
                                                const float* __restrict__ w_value,
                                                const float* __restrict__ weight,
                                                unsigned short* __restrict__ WT) {
    __shared__ float a2[F_];
    __shared__ float wred[4];
    const int c    = blockIdx.x >> 2;
    const int part = blockIdx.x & 3;   // 64 features each for the prep phase
    const int t    = threadIdx.x;

    // sum the 16 second-level partials for (c, f=t): coalesced, fully parallel
    const float* gp = G2 + c * F_ + t;
    float g0 = 0.f, g1 = 0.f, g2 = 0.f, g3 = 0.f;
#pragma unroll
    for (int i = 0; i < NG2; i += 4) {
        g0 += gp[(size_t)(i + 0) * C_ * F_];
        g1 += gp[(size_t)(i + 1) * C_ * F_];
        g2 += gp[(size_t)(i + 2) * C_ * F_];
        g3 += gp[(size_t)(i + 3) * C_ * F_];
    }
    float g = (g0 + g1) + (g2 + g3);

    float s = 0.f;
#pragma unroll
    for (int k = 0; k < DK_; ++k) s += w_key[c * DK_ + k] * w_query[c * DK_ + k];

    float z = s * g * (1.0f / (float)B_);
    float m = z;
#pragma unroll
    for (int off = 32; off >= 1; off >>= 1) m = fmaxf(m, __shfl_xor(m, off));
    if ((t & 63) == 0) wred[t >> 6] = m;
    __syncthreads();
    float mm = fmaxf(fmaxf(wred[0], wred[1]), fmaxf(wred[2], wred[3]));
    a2[t] = expf(z - mm) * w_value[c];
    __syncthreads();

    const int o  = t & 63;
    const int fg = t >> 6;
    const float* wsrc = weight + (size_t)c * F_ * O_;
    char* wdst = (char*)(WT + (size_t)c * O_ * F_);
#pragma unroll
    for (int gi = 0; gi < 2; ++gi) {
        int f0 = part * 64 + fg * 16 + gi * 8;
        short8 v8;
#pragma unroll
        for (int e = 0; e < 8; ++e) {
            int f = f0 + e;
            v8[e] = (short)f2bf(wsrc[f * O_ + o] * a2[f]);  // coalesced along o
        }
        int byte = o * 512 + ((2 * f0) ^ ((o & 7) << 4));   // 16B-aligned
        *(short8*)(wdst + byte) = v8;
    }
}

// ---------------- K3: out[c][b][o] = Xbf16 @ WT[c]^T + bias, MFMA 16x16x32 ---
// 64-row tiles, 4 waves x 16 rows, A prefetched to regs before staging barrier
__global__ __launch_bounds__(256) void k3_mfma(const unsigned short* __restrict__ xb,
                                               const unsigned short* __restrict__ WT,
                                               const float* __restrict__ bias,
                                               float* __restrict__ out) {
    __shared__ unsigned short wt[O_ * F_];  // 32 KiB swizzled [o][k]
    const int c  = blockIdx.y;
    const int b0 = blockIdx.x * 64;
    const int t  = threadIdx.x;
    const int w  = t >> 6;
    const int l  = t & 63;
    const int lr = l & 15;
    const int lg = l >> 4;

    // A prefetch: 8 x short8 (row b0+w*16+lr, k = k0*32 + lg*8), issues early
    const unsigned short* xrow = xb + (size_t)(b0 + w * 16 + lr) * F_;
    short8 a[8];
#pragma unroll
    for (int k0 = 0; k0 < 8; ++k0) a[k0] = *(const short8*)(xrow + k0 * 32 + lg * 8);

    // stage WT[c] linearly (swizzle pre-baked)
    {
        const short8* src = (const short8*)(WT + (size_t)c * O_ * F_);
        short8* dst = (short8*)wt;
#pragma unroll
        for (int j = 0; j < 8; ++j) dst[t + 256 * j] = src[t + 256 * j];
    }
    __syncthreads();

    floatx4 acc[4];
#pragma unroll
    for (int n = 0; n < 4; ++n) {
        float bo = bias[c * O_ + n * 16 + lr];
        acc[n] = (floatx4){bo, bo, bo, bo};   // bias folded into C-init
    }

#pragma unroll
    for (int k0 = 0; k0 < 8; ++k0) {
#pragma unroll
        for (int n = 0; n < 4; ++n) {
            int o = n * 16 + lr;
            int byte = o * 512 + ((k0 * 64 + lg * 16) ^ ((o & 7) << 4));
            short8 bf = *(const short8*)((const char*)wt + byte);  // conflict-free
            acc[n] = __builtin_amdgcn_mfma_f32_16x16x32_bf16(a[k0], bf, acc[n], 0, 0, 0);
        }
    }

    // D layout: col = lane&15, row = (lane>>4)*4 + reg
#pragma unroll
    for (int n = 0; n < 4; ++n) {
        int col = n * 16 + lr;
#pragma unroll
        for (int r = 0; r < 4; ++r) {
            int row = b0 + w * 16 + lg * 4 + r;
            out[((size_t)c * B_ + row) * O_ + col] = acc[n][r];
        }
    }
}

extern "C" void kernel_launch(void* const* d_in, const int* in_sizes, int n_in,
                              void* d_out, int out_size, void* d_ws, size_t ws_size,
                              hipStream_t stream) {
    const float* x       = (const float*)d_in[0];
    const float* y       = (const float*)d_in[1];
    const float* w_key   = (const float*)d_in[2];
    const float* w_query = (const float*)d_in[3];
    const float* w_value = (const float*)d_in[4];
    const float* weight  = (const float*)d_in[5];
    const float* bias    = (const float*)d_in[6];
    float* out = (float*)d_out;

    char* ws = (char*)d_ws;
    unsigned short* xb     = (unsigned short*)ws;                                  // 4 MiB
    unsigned short* WT     = (unsigned short*)(ws + (size_t)B_ * F_ * 2);          // 320 KiB
    float*          G_part = (float*)(ws + (size_t)B_ * F_ * 2 + C_ * O_ * F_ * 2);          // 2.62 MiB
    float*          G2     = G_part + (size_t)NBLK1 * C_ * F_;                     // 160 KiB

    k1_reduce<<<NBLK1, 256, 0, stream>>>(x, y, G_part, xb);
    k1b_reduce<<<C_ * NG2, 256, 0, stream>>>(G_part, G2);
    k2_wprep<<<C_ * 4, 256, 0, stream>>>(G2, w_key, w_query, w_value, weight, WT);
    dim3 g3(B_ / 64, C_);
    k3_mfma<<<g3, 256, 0, stream>>>(xb, WT, bias, out);
}